// Round 4
// baseline (207.092 us; speedup 1.0000x reference)
//
#include <hip/hip_runtime.h>
#include <hip/hip_bf16.h>

#define NXC 440
#define NYC 500
#define GCELLS (NXC * NYC)          // 220000 (NZ = 1)
#define MAXV 40000
#define MAXP 32
#define CPB 1024                    // cells per scan block (256 thr * 4)
#define NBLK ((GCELLS + CPB - 1) / CPB)  // 215

// Expected outputs are bf16-quantized but STORED as fp32. Round-trip our
// fp32 results through bf16 so we match the expected side bit-exactly.
__device__ __forceinline__ float bf16r(float x) {
    return __bfloat162float(__float2bfloat16(x));
}

// Linear cell index exactly as the numpy reference (fp32 ops). Invalid -> -1.
__device__ __forceinline__ int point_cell(const float* p) {
    float x = p[0], y = p[1], z = p[2];
    bool valid = (x >= 0.0f) && (x < 70.4f) &&
                 (y >= -40.0f) && (y < 40.0f) &&
                 (z >= -3.0f) && (z < 1.0f);
    if (!valid) return -1;
    int cx = (int)floorf((x - 0.0f) / 0.16f);
    int cy = (int)floorf((y + 40.0f) / 0.16f);
    // cz: z in [-3,1) -> floor((z+3)/4) == 0 always; NZ==1
    cx = min(max(cx, 0), NXC - 1);
    cy = min(max(cy, 0), NYC - 1);
    return cy * NXC + cx;
}

// Pass 1: per-cell histogram (+ optional cellid cache).
__global__ __launch_bounds__(256) void k_count(const float* pts, int* cnt, int* cellid, int n) {
    int i = blockIdx.x * 256 + threadIdx.x;
    if (i >= n) return;
    int cell = point_cell(pts + (size_t)i * 5);
    if (cellid) cellid[i] = cell;
    if (cell >= 0) atomicAdd(&cnt[cell], 1);
}

// Per-block occupancy sums over CPB cells.
__global__ __launch_bounds__(256) void k_bsum(const int* cnt, int* bso) {
    __shared__ int so[256];
    int b = blockIdx.x, t = threadIdx.x;
    int o = 0;
    int base = b * CPB + t * 4;
    #pragma unroll
    for (int k = 0; k < 4; ++k) {
        int cell = base + k;
        if (cell < GCELLS) o += (cnt[cell] > 0);
    }
    so[t] = o;
    __syncthreads();
    for (int d = 128; d > 0; d >>= 1) {
        if (t < d) so[t] += so[t + d];
        __syncthreads();
    }
    if (t == 0) bso[b] = so[0];
}

// Single-block exclusive scan of the NBLK block sums (NBLK <= 256).
__global__ __launch_bounds__(256) void k_scan_top(int* bso, int nblk) {
    __shared__ int so[256];
    int t = threadIdx.x;
    so[t] = (t < nblk) ? bso[t] : 0;
    __syncthreads();
    for (int d = 1; d < 256; d <<= 1) {
        int vo = (t >= d) ? so[t - d] : 0;
        __syncthreads();
        so[t] += vo;
        __syncthreads();
    }
    if (t < nblk) bso[t] = (t > 0) ? so[t - 1] : 0;  // exclusive
}

// Per-cell occupancy scan -> voxel ids; emit coords/num_points/vox_cnt for kept voxels.
__global__ __launch_bounds__(256) void k_scan(const int* cnt, const int* bso,
                                              int* voxid, int* vox_cnt,
                                              float* out_coords, float* out_np) {
    __shared__ int so[256];
    int b = blockIdx.x, t = threadIdx.x;
    int base = b * CPB + t * 4;
    int c[4];
    int o = 0;
    #pragma unroll
    for (int k = 0; k < 4; ++k) {
        int cell = base + k;
        c[k] = (cell < GCELLS) ? cnt[cell] : 0;
        o += (c[k] > 0);
    }
    so[t] = o;
    __syncthreads();
    for (int d = 1; d < 256; d <<= 1) {
        int vo = (t >= d) ? so[t - d] : 0;
        __syncthreads();
        so[t] += vo;
        __syncthreads();
    }
    int eo = ((t > 0) ? so[t - 1] : 0) + bso[b];
    #pragma unroll
    for (int k = 0; k < 4; ++k) {
        int cell = base + k;
        if (cell < GCELLS) {
            int cc = c[k];
            bool occ = cc > 0;
            bool kept = occ && (eo < MAXV);
            voxid[cell] = kept ? eo : 0x7fffffff;
            if (kept) {
                int cy = cell / NXC;
                int cx = cell - cy * NXC;
                out_coords[(size_t)eo * 3 + 0] = 0.0f;                // cz
                out_coords[(size_t)eo * 3 + 1] = bf16r((float)cy);
                out_coords[(size_t)eo * 3 + 2] = bf16r((float)cx);
                out_np[eo] = bf16r((float)min(cc, MAXP));
                vox_cnt[eo] = cc;
            }
            eo += occ ? 1 : 0;
        }
    }
}

// Scatter point indices into fixed-stride per-voxel segments (arbitrary order).
__global__ __launch_bounds__(256) void k_scatter(const float* pts, const int* cellid,
                                                 const int* voxid,
                                                 int* ticket, int* seg, int S, int n) {
    int i = blockIdx.x * 256 + threadIdx.x;
    if (i >= n) return;
    int cell = cellid ? cellid[i] : point_cell(pts + (size_t)i * 5);
    if (cell < 0) return;
    int v = voxid[cell];
    if (v >= MAXV) return;
    int t = atomicAdd(&ticket[v], 1);
    if (t < S) seg[(size_t)v * S + t] = i;
}

// One wave per voxel: rank segment entries by original index (stable order),
// gather features for ranks < 32, store fp32 (bf16-rounded).
__global__ __launch_bounds__(256) void k_fill(const float* pts, const int* vox_cnt,
                                              const int* seg, int S,
                                              float* out_vox) {
    int wave = threadIdx.x >> 6;
    int lane = threadIdx.x & 63;
    int v = blockIdx.x * 4 + wave;
    if (v >= MAXV) return;
    int n = vox_cnt[v];
    if (n <= 0) return;       // unused voxel slot (zeroed by memset)
    n = min(n, S);            // segment capacity (S >= 32; P(cc>32) ~ 1e-10)
    int myidx = (lane < n) ? seg[(size_t)v * S + lane] : 0x7fffffff;
    int rank = 0;
    for (int j = 0; j < n; ++j) {
        int ej = __shfl(myidx, j, 64);
        rank += (ej < myidx) ? 1 : 0;
    }
    if (lane < n && rank < MAXP) {
        const float* src = pts + (size_t)myidx * 5;
        float* dst = out_vox + ((size_t)v * MAXP + rank) * 5;
        #pragma unroll
        for (int k = 0; k < 5; ++k) dst[k] = bf16r(src[k]);
    }
}

extern "C" void kernel_launch(void* const* d_in, const int* in_sizes, int n_in,
                              void* d_out, int out_size, void* d_ws, size_t ws_size,
                              hipStream_t stream) {
    const float* pts = (const float*)d_in[0];
    int n = in_sizes[0] / 5;

    float* out = (float*)d_out;              // fp32 storage, bf16-precision values
    float* out_vox    = out;                                   // MAXV*32*5
    float* out_coords = out + (size_t)MAXV * MAXP * 5;         // MAXV*3
    float* out_np     = out_coords + (size_t)MAXV * 3;         // MAXV

    // Workspace sizing: adapt segment capacity / cellid cache to ws_size so we
    // never write past d_ws.
    const size_t base_ints = (size_t)GCELLS + MAXV + MAXV + GCELLS + 256;  // 520,256
    int S = 32; bool use_cid = false;
    {
        auto fits = [&](int s, bool cid) {
            return (base_ints + (size_t)MAXV * s + (cid ? (size_t)n : 0)) * sizeof(int) <= ws_size;
        };
        if      (fits(64, true))  { S = 64; use_cid = true;  }
        else if (fits(64, false)) { S = 64; use_cid = false; }
        else if (fits(48, false)) { S = 48; use_cid = false; }
        else if (fits(40, false)) { S = 40; use_cid = false; }
        else                      { S = 32; use_cid = false; }
    }

    int* ws      = (int*)d_ws;
    int* cnt     = ws;                     // GCELLS   (zeroed)
    int* ticket  = cnt + GCELLS;           // MAXV     (zeroed)
    int* vox_cnt = ticket + MAXV;          // MAXV     (zeroed)
    int* voxid   = vox_cnt + MAXV;         // GCELLS
    int* bso     = voxid + GCELLS;         // 256
    int* cellid  = use_cid ? (bso + 256) : nullptr;          // n (optional)
    int* seg     = (bso + 256) + (use_cid ? (size_t)n : 0);  // MAXV * S

    // Zero outputs (harness poisons 0xAA before every timed launch) and the
    // atomically-updated counters (cnt, ticket, vox_cnt are contiguous).
    hipMemsetAsync(out, 0, (size_t)out_size * sizeof(float), stream);
    hipMemsetAsync(cnt, 0, (size_t)(GCELLS + 2 * MAXV) * sizeof(int), stream);

    int nb = (n + 255) / 256;
    k_count<<<nb, 256, 0, stream>>>(pts, cnt, cellid, n);
    k_bsum<<<NBLK, 256, 0, stream>>>(cnt, bso);
    k_scan_top<<<1, 256, 0, stream>>>(bso, NBLK);
    k_scan<<<NBLK, 256, 0, stream>>>(cnt, bso, voxid, vox_cnt, out_coords, out_np);
    k_scatter<<<nb, 256, 0, stream>>>(pts, cellid, voxid, ticket, seg, S, n);
    k_fill<<<(MAXV + 3) / 4, 256, 0, stream>>>(pts, vox_cnt, seg, S, out_vox);
}